// Round 5
// baseline (617.339 us; speedup 1.0000x reference)
//
#include <hip/hip_runtime.h>

typedef __attribute__((ext_vector_type(8))) short short8;
typedef __attribute__((ext_vector_type(4))) float f32x4;
typedef __attribute__((ext_vector_type(4))) unsigned short u16x4;

#define NB 8
#define NQL 2048
#define NKL 2048
#define DD 512

static __device__ __forceinline__ unsigned short f2bf(float x){
  unsigned u = __builtin_bit_cast(unsigned, x);
  unsigned r = u + 0x7FFFu + ((u >> 16) & 1u);
  return (unsigned short)(r >> 16);
}
static __device__ __forceinline__ float bf2f(unsigned short h){
  unsigned u = ((unsigned)h) << 16;
  return __builtin_bit_cast(float, u);
}

static __device__ __forceinline__ void stage16(const unsigned short* g, unsigned short* l){
  __builtin_amdgcn_global_load_lds(
      (const __attribute__((address_space(1))) void*)g,
      (__attribute__((address_space(3))) void*)l, 16, 0, 0);
}

static __device__ __forceinline__ void barrier_lgkm(){
  asm volatile("s_waitcnt lgkmcnt(0)" ::: "memory");
  __builtin_amdgcn_s_barrier();
  asm volatile("" ::: "memory");
}

// ---------------- split fp32 -> bf16 hi/lo (W matrices only) ----------------
__global__ __launch_bounds__(256) void split_k(const float* __restrict__ x,
    unsigned short* __restrict__ hi, unsigned short* __restrict__ lo, int n4){
  int i = blockIdx.x*256 + threadIdx.x;
  if (i >= n4) return;
  f32x4 v = reinterpret_cast<const f32x4*>(x)[i];
  u16x4 h, l;
  #pragma unroll
  for (int j=0;j<4;j++){
    unsigned short hh = f2bf(v[j]);
    h[j] = hh;
    l[j] = f2bf(v[j] - bf2f(hh));
  }
  reinterpret_cast<u16x4*>(hi)[i] = h;
  reinterpret_cast<u16x4*>(lo)[i] = l;
}

// ---------------- fused projections: Y = X * W^T (128x128 tile, staged, dbuf) ----------------
// z=0: Q flat hi/lo [16384][512]
// z=1: K tiles [b][kt][2][32][512], col-group ^ (row&7)
// z=2: V^T flat hi/lo [b][512][2048]
__global__ __launch_bounds__(256, 2) void proj2_k(
    const float* __restrict__ Xq, const float* __restrict__ Xk, const float* __restrict__ Xv,
    const unsigned short* __restrict__ Wqh, const unsigned short* __restrict__ Wql,
    const unsigned short* __restrict__ Wkh, const unsigned short* __restrict__ Wkl,
    const unsigned short* __restrict__ Wvh, const unsigned short* __restrict__ Wvl,
    unsigned short* __restrict__ Yqh, unsigned short* __restrict__ Yql,
    unsigned short* __restrict__ Ykt,
    unsigned short* __restrict__ Yvth, unsigned short* __restrict__ Yvtl)
{
  __shared__ unsigned short AB[2][4][128][32];   // 64 KB

  const int z = blockIdx.z;
  const float* X          = (z==0) ? Xq  : (z==1) ? Xk  : Xv;
  const unsigned short* Wh = (z==0) ? Wqh : (z==1) ? Wkh : Wvh;
  const unsigned short* Wl = (z==0) ? Wql : (z==1) ? Wkl : Wvl;

  const int mbase = blockIdx.x * 128;
  const int nbase = blockIdx.y * 128;
  const int tid = threadIdx.x;
  const int w = tid >> 6, lane = tid & 63;
  const int l15 = lane & 15, l4 = lane >> 4;
  const int wr = w >> 1, wc = w & 1;

  const int arow = tid >> 1, ahalf = tid & 1;
  const int brow_l = w*16 + (lane>>2);
  const int bkg    = (lane & 3) ^ ((lane >> 3) & 3);

  f32x4 acc[4][4];
  #pragma unroll
  for (int m=0;m<4;m++)
    #pragma unroll
    for (int n=0;n<4;n++) acc[m][n] = (f32x4){0.f,0.f,0.f,0.f};

  f32x4 xa[4];
  {
    const f32x4* xp = reinterpret_cast<const f32x4*>(X + (size_t)(mbase+arow)*DD + ahalf*16);
    #pragma unroll
    for (int q=0;q<4;q++) xa[q] = xp[q];
  }
  {
    unsigned short* lB = &AB[0][2][0][0] + w*512;
    #pragma unroll
    for (int r=0;r<2;r++){
      const size_t gh = (size_t)(nbase + r*64 + brow_l)*DD + bkg*8;
      stage16(Wh + gh, lB + r*2048);
      stage16(Wl + gh, lB + 4096 + r*2048);
    }
  }
  {
    asm volatile("s_waitcnt vmcnt(4)" ::: "memory");
    short8 h0,h1,l0,l1;
    #pragma unroll
    for (int q=0;q<2;q++){
      #pragma unroll
      for (int j=0;j<4;j++){
        float v0 = xa[q*2][j], v1 = xa[q*2+1][j];
        unsigned short a = f2bf(v0); unsigned short b = f2bf(v1);
        if (q==0){ h0[j]=(short)a; h0[4+j]=(short)b; l0[j]=(short)f2bf(v0-bf2f(a)); l0[4+j]=(short)f2bf(v1-bf2f(b)); }
        else     { h1[j]=(short)a; h1[4+j]=(short)b; l1[j]=(short)f2bf(v0-bf2f(a)); l1[4+j]=(short)f2bf(v1-bf2f(b)); }
      }
    }
    const int sw = (arow>>1)&3;
    const int cg0 = (ahalf*2) ^ sw, cg1 = (ahalf*2+1) ^ sw;
    *reinterpret_cast<short8*>(&AB[0][0][arow][cg0*8]) = h0;
    *reinterpret_cast<short8*>(&AB[0][0][arow][cg1*8]) = h1;
    *reinterpret_cast<short8*>(&AB[0][1][arow][cg0*8]) = l0;
    *reinterpret_cast<short8*>(&AB[0][1][arow][cg1*8]) = l1;
  }

  const int asw = (l15>>1)&3;

  #pragma unroll 1
  for (int s=0; s<16; ++s){
    const int cur = s&1, nxt = cur^1;
    asm volatile("s_waitcnt vmcnt(0)" ::: "memory");
    barrier_lgkm();

    if (s < 15){
      const f32x4* xp = reinterpret_cast<const f32x4*>(X + (size_t)(mbase+arow)*DD + (s+1)*32 + ahalf*16);
      #pragma unroll
      for (int q=0;q<4;q++) xa[q] = xp[q];
      unsigned short* lB = &AB[nxt][2][0][0] + w*512;
      #pragma unroll
      for (int r=0;r<2;r++){
        const size_t gh = (size_t)(nbase + r*64 + brow_l)*DD + (s+1)*32 + bkg*8;
        stage16(Wh + gh, lB + r*2048);
        stage16(Wl + gh, lB + 4096 + r*2048);
      }
    }

    short8 ah[4], al[4], bh[4], bl[4];
    #pragma unroll
    for (int m=0;m<4;m++){
      const int rA = wr*64 + m*16 + l15;
      const int cg = (l4 ^ asw)*8;
      ah[m] = *reinterpret_cast<const short8*>(&AB[cur][0][rA][cg]);
      al[m] = *reinterpret_cast<const short8*>(&AB[cur][1][rA][cg]);
    }
    #pragma unroll
    for (int n=0;n<4;n++){
      const int rB = wc*64 + n*16 + l15;
      const int cg = (l4 ^ asw)*8;
      bh[n] = *reinterpret_cast<const short8*>(&AB[cur][2][rB][cg]);
      bl[n] = *reinterpret_cast<const short8*>(&AB[cur][3][rB][cg]);
    }
    #pragma unroll
    for (int m=0;m<4;m++)
      #pragma unroll
      for (int n=0;n<4;n++) acc[m][n] = __builtin_amdgcn_mfma_f32_16x16x32_bf16(ah[m], bh[n], acc[m][n], 0,0,0);
    #pragma unroll
    for (int m=0;m<4;m++)
      #pragma unroll
      for (int n=0;n<4;n++) acc[m][n] = __builtin_amdgcn_mfma_f32_16x16x32_bf16(ah[m], bl[n], acc[m][n], 0,0,0);
    #pragma unroll
    for (int m=0;m<4;m++)
      #pragma unroll
      for (int n=0;n<4;n++) acc[m][n] = __builtin_amdgcn_mfma_f32_16x16x32_bf16(al[m], bh[n], acc[m][n], 0,0,0);

    if (s < 15){
      asm volatile("s_waitcnt vmcnt(4)" ::: "memory");
      short8 h0,h1,l0,l1;
      #pragma unroll
      for (int q=0;q<2;q++){
        #pragma unroll
        for (int j=0;j<4;j++){
          float v0 = xa[q*2][j], v1 = xa[q*2+1][j];
          unsigned short a = f2bf(v0); unsigned short b = f2bf(v1);
          if (q==0){ h0[j]=(short)a; h0[4+j]=(short)b; l0[j]=(short)f2bf(v0-bf2f(a)); l0[4+j]=(short)f2bf(v1-bf2f(b)); }
          else     { h1[j]=(short)a; h1[4+j]=(short)b; l1[j]=(short)f2bf(v0-bf2f(a)); l1[4+j]=(short)f2bf(v1-bf2f(b)); }
        }
      }
      const int sw = (arow>>1)&3;
      const int cg0 = (ahalf*2) ^ sw, cg1 = (ahalf*2+1) ^ sw;
      *reinterpret_cast<short8*>(&AB[nxt][0][arow][cg0*8]) = h0;
      *reinterpret_cast<short8*>(&AB[nxt][0][arow][cg1*8]) = h1;
      *reinterpret_cast<short8*>(&AB[nxt][1][arow][cg0*8]) = l0;
      *reinterpret_cast<short8*>(&AB[nxt][1][arow][cg1*8]) = l1;
    }
  }

  #pragma unroll
  for (int m=0;m<4;m++){
    #pragma unroll
    for (int n=0;n<4;n++){
      #pragma unroll
      for (int j=0;j<4;j++){
        const int row = mbase + wr*64 + m*16 + l4*4 + j;
        const int col = nbase + wc*64 + n*16 + l15;
        const float y = acc[m][n][j];
        const unsigned short h = f2bf(y);
        const unsigned short l = f2bf(y - bf2f(h));
        if (z == 0){
          const size_t idx = (size_t)row*DD + col;
          Yqh[idx] = h; Yql[idx] = l;
        } else if (z == 1){
          const int bb = row >> 11, nn = row & 2047, kt = nn >> 5;
          const size_t tb = ((size_t)(bb*64 + kt)) << 15;
          const int kr = nn & 31, cg = col >> 3, ci = col & 7;
          const size_t idxH = tb + ((size_t)kr)*512 + (size_t)((((cg ^ (kr & 7)) << 3)) | ci);
          Ykt[idxH] = h; Ykt[idxH + 16384] = l;
        } else {
          const int bb = row >> 11, nn = row & 2047;
          const size_t idx = ((size_t)(bb*DD + col))*NKL + nn;
          Yvth[idx] = h; Yvtl[idx] = l;
        }
      }
    }
  }
}

// ---------------- fused flash attention: K double-buffered LDS, V direct from L2 ----------------
// Grid 256 (b = bid&7 XCD-aligned, qt = bid>>3), 512 threads (8 waves).
// S^T = mfma(K,Q) -> in-register softmax. K(t+1) staged into other buffer at TOP of
// step t (full-step prefetch lead). V^T read per-wave from global (L2-resident),
// latency hidden under PV MFMA. 3 barriers/step, one vmcnt wall (pre-drained).
__global__ __launch_bounds__(512, 2) void attn_k(
    const unsigned short* __restrict__ Qhi, const unsigned short* __restrict__ Qlo,
    const unsigned short* __restrict__ Kt,
    const unsigned short* __restrict__ Vth, const unsigned short* __restrict__ Vtl,
    float* __restrict__ Out)
{
  __shared__ unsigned short K_lds[2][2][32][512];  // 128 KB (dbuf, hi/lo, row, swizzled col)
  __shared__ unsigned short Phi_s[64][40];
  __shared__ unsigned short Plo_s[64][40];         // 10 KB
  __shared__ float pm_s[64][2], ps_s[64][2];
  __shared__ float m_s[2][64], l_s[64], sc_s[64];

  const int bid = blockIdx.x;
  const int b  = bid & 7;
  const int qt = bid >> 3;
  const int tid = threadIdx.x;
  const int w = tid >> 6, lane = tid & 63;
  const int l15 = lane & 15, l4 = lane >> 4;
  const int rw = w & 3,  cw = w >> 2;   // S^T frag: q-rows rw*16.., k-cols cw*16..
  const int orw = w >> 2, ocw = w & 3;  // O: rows orw*32.., cols ocw*128..

  short8 qhf[16], qlf[16];
  {
    const size_t qoff = (size_t)(b*NQL + qt*64 + rw*16 + l15)*DD + l4*8;
    #pragma unroll
    for (int kc=0;kc<16;kc++){
      qhf[kc] = *reinterpret_cast<const short8*>(Qhi + qoff + kc*32);
      qlf[kc] = *reinterpret_cast<const short8*>(Qlo + qoff + kc*32);
    }
  }

  f32x4 o[2][8];
  #pragma unroll
  for (int i=0;i<2;i++)
    #pragma unroll
    for (int j=0;j<8;j++) o[i][j] = (f32x4){0.f,0.f,0.f,0.f};

  if (tid < 64){ m_s[0][tid] = -1e30f; l_s[tid] = 0.f; }

  const unsigned short* gK  = Kt  + ((size_t)(b*64) << 15);
  const unsigned short* gVh = Vth + (size_t)b*DD*NKL;
  const unsigned short* gVl = Vtl + (size_t)b*DD*NKL;
  const int goff  = w*512 + lane*8;
  const int lbase = w*512;

  // prologue: stage K(0) into buf 0
  {
    unsigned short* lK = &K_lds[0][0][0][0];
    #pragma unroll
    for (int r=0;r<8;r++) stage16(gK + r*4096 + goff, lK + r*4096 + lbase);
  }

  const int krow = cw*16 + l15;
  const int kx = krow & 7;
  const int row_i = rw*16 + l15;     // this lane's q-row (local)

  #pragma unroll 1
  for (int kt=0; kt<64; ++kt){
    const int par = kt & 1;
    asm volatile("s_waitcnt vmcnt(0)" ::: "memory");   // K(kt) resident (issued a full step ago)
    barrier_lgkm();                                    // bar A

    // stage K(kt+1) into the OTHER buffer — waited one full step later
    {
      const unsigned short* g = gK + ((size_t)((kt+1)&63) << 15);
      unsigned short* lK = &K_lds[par^1][0][0][0];
      #pragma unroll
      for (int r=0;r<8;r++) stage16(g + r*4096 + goff, lK + r*4096 + lbase);
    }

    // ---- S^T = K Q^T (swapped operands) ----
    f32x4 shh = (f32x4){0.f,0.f,0.f,0.f};
    f32x4 shl = (f32x4){0.f,0.f,0.f,0.f};
    f32x4 slh = (f32x4){0.f,0.f,0.f,0.f};
    __builtin_amdgcn_s_setprio(1);
    #pragma unroll
    for (int kc=0;kc<16;kc++){
      const int cg = ((kc*4 + l4) ^ kx) << 3;
      const short8 kh = *reinterpret_cast<const short8*>(&K_lds[par][0][krow][cg]);
      const short8 kl = *reinterpret_cast<const short8*>(&K_lds[par][1][krow][cg]);
      shh = __builtin_amdgcn_mfma_f32_16x16x32_bf16(kh, qhf[kc], shh, 0,0,0);
      shl = __builtin_amdgcn_mfma_f32_16x16x32_bf16(kl, qhf[kc], shl, 0,0,0);
      slh = __builtin_amdgcn_mfma_f32_16x16x32_bf16(kh, qlf[kc], slh, 0,0,0);
    }
    __builtin_amdgcn_s_setprio(0);
    const f32x4 sv = shh + shl + slh;   // sv[r] = S[row_i][cw*16 + l4*4 + r]

    // ---- per-wave softmax partials ----
    float mw = fmaxf(fmaxf(sv[0],sv[1]), fmaxf(sv[2],sv[3]));
    mw = fmaxf(mw, __shfl_xor(mw, 16));
    mw = fmaxf(mw, __shfl_xor(mw, 32));
    float p0 = __expf(sv[0]-mw), p1 = __expf(sv[1]-mw);
    float p2 = __expf(sv[2]-mw), p3 = __expf(sv[3]-mw);
    float ssum = p0+p1+p2+p3;
    ssum += __shfl_xor(ssum, 16);
    ssum += __shfl_xor(ssum, 32);
    if (l4 == 0){ pm_s[row_i][cw] = mw; ps_s[row_i][cw] = ssum; }
    barrier_lgkm();                                    // bar B — partials ready

    // ---- combine partials, finalize P, write P hi/lo ----
    {
      const float m0 = pm_s[row_i][0], m1 = pm_s[row_i][1];
      const float m_old = m_s[par][row_i];
      const float m_new = fmaxf(fmaxf(m0, m1), m_old);
      const float c = __expf(mw - m_new);
      p0 *= c; p1 *= c; p2 *= c; p3 *= c;
      if (cw == 0 && l4 == 0){
        const float e_old = __expf(m_old - m_new);
        const float e1    = __expf(m1 - m_new);
        l_s[row_i] = l_s[row_i]*e_old + ps_s[row_i][0]*c + ps_s[row_i][1]*e1;
        m_s[par^1][row_i] = m_new;
        sc_s[row_i] = e_old;
      }
      const unsigned short h0=f2bf(p0), h1=f2bf(p1), h2=f2bf(p2), h3=f2bf(p3);
      uint2 hv, lv;
      hv.x = (unsigned)h0 | ((unsigned)h1<<16);
      hv.y = (unsigned)h2 | ((unsigned)h3<<16);
      lv.x = (unsigned)f2bf(p0-bf2f(h0)) | ((unsigned)f2bf(p1-bf2f(h1))<<16);
      lv.y = (unsigned)f2bf(p2-bf2f(h2)) | ((unsigned)f2bf(p3-bf2f(h3))<<16);
      *reinterpret_cast<uint2*>(&Phi_s[row_i][cw*16 + l4*4]) = hv;
      *reinterpret_cast<uint2*>(&Plo_s[row_i][cw*16 + l4*4]) = lv;
    }
    barrier_lgkm();                                    // bar C — P ready

    // ---- rescale O (skip when running max unchanged) ----
    {
      float scs[2][4];
      bool need = false;
      #pragma unroll
      for (int pr=0; pr<2; pr++)
        #pragma unroll
        for (int j=0;j<4;j++){
          const float s0 = sc_s[orw*32 + pr*16 + l4*4 + j];
          scs[pr][j] = s0;
          need = need || (s0 < 0.999999f);
        }
      if (__any(need)){
        #pragma unroll
        for (int pr=0;pr<2;pr++)
          #pragma unroll
          for (int c=0;c<8;c++)
            #pragma unroll
            for (int j=0;j<4;j++) o[pr][c][j] *= scs[pr][j];
      }
    }

    // ---- O += P V : P from LDS, V^T direct from global (L2) ----
    short8 pah[2], pal[2];
    #pragma unroll
    for (int pr=0;pr<2;pr++){
      const int prow = orw*32 + pr*16 + l15;
      pah[pr] = *reinterpret_cast<const short8*>(&Phi_s[prow][l4*8]);
      pal[pr] = *reinterpret_cast<const short8*>(&Plo_s[prow][l4*8]);
    }
    __builtin_amdgcn_s_setprio(1);
    #pragma unroll
    for (int cc=0; cc<8; ++cc){
      const size_t vo = (size_t)(ocw*128 + cc*16 + l15)*NKL + kt*32 + l4*8;
      const short8 vh = *reinterpret_cast<const short8*>(gVh + vo);
      const short8 vl = *reinterpret_cast<const short8*>(gVl + vo);
      o[0][cc] = __builtin_amdgcn_mfma_f32_16x16x32_bf16(pah[0], vh, o[0][cc], 0,0,0);
      o[1][cc] = __builtin_amdgcn_mfma_f32_16x16x32_bf16(pah[1], vh, o[1][cc], 0,0,0);
      o[0][cc] = __builtin_amdgcn_mfma_f32_16x16x32_bf16(pal[0], vh, o[0][cc], 0,0,0);
      o[1][cc] = __builtin_amdgcn_mfma_f32_16x16x32_bf16(pal[1], vh, o[1][cc], 0,0,0);
      o[0][cc] = __builtin_amdgcn_mfma_f32_16x16x32_bf16(pah[0], vl, o[0][cc], 0,0,0);
      o[1][cc] = __builtin_amdgcn_mfma_f32_16x16x32_bf16(pah[1], vl, o[1][cc], 0,0,0);
    }
    __builtin_amdgcn_s_setprio(0);
    // no barrier here: bar A orders P reuse; K buffers are parity-separated
  }

  barrier_lgkm();   // l_s final visible

  #pragma unroll
  for (int pr=0;pr<2;pr++){
    #pragma unroll
    for (int j=0;j<4;j++){
      const int row = orw*32 + pr*16 + l4*4 + j;
      const float inv = 1.0f / l_s[row];
      const size_t obase = (size_t)(b*NQL + qt*64 + row)*DD;
      #pragma unroll
      for (int c=0;c<8;c++){
        const int col = ocw*128 + c*16 + l15;
        Out[obase + col] = o[pr][c][j]*inv;
      }
    }
  }
}

extern "C" void kernel_launch(void* const* d_in, const int* in_sizes, int n_in,
                              void* d_out, int out_size, void* d_ws, size_t ws_size,
                              hipStream_t stream) {
  const float* query = (const float*)d_in[0];
  const float* key   = (const float*)d_in[1];
  const float* value = (const float*)d_in[2];
  const float* Wq    = (const float*)d_in[3];
  const float* Wk    = (const float*)d_in[4];
  const float* Wv    = (const float*)d_in[5];
  float* out = (float*)d_out;

  const size_t SB = (size_t)NB*NQL*DD;
  const size_t WB = (size_t)DD*DD;

  unsigned short* p = (unsigned short*)d_ws;
  unsigned short *wqh = p,        *wql = p +   WB;
  unsigned short *wkh = p + 2*WB, *wkl = p + 3*WB;
  unsigned short *wvh = p + 4*WB, *wvl = p + 5*WB;
  unsigned short* q0 = p + 6*WB;
  unsigned short *qh  = q0,        *ql  = q0 + SB;
  unsigned short *Ktl = q0 + 2*SB;            // [8][64][2][32][512] = 2*SB
  unsigned short *Vth = q0 + 4*SB;            // [8][512][2048]      = SB
  unsigned short *Vtl = q0 + 5*SB;            // [8][512][2048]      = SB

  split_k<<<256, 256, 0, stream>>>(Wq, wqh, wql, (int)(WB/4));
  split_k<<<256, 256, 0, stream>>>(Wk, wkh, wkl, (int)(WB/4));
  split_k<<<256, 256, 0, stream>>>(Wv, wvh, wvl, (int)(WB/4));

  dim3 pg(128, 4, 3);
  proj2_k<<<pg, 256, 0, stream>>>(query, key, value,
                                  wqh, wql, wkh, wkl, wvh, wvl,
                                  qh, ql, Ktl, Vth, Vtl);

  attn_k<<<256, 512, 0, stream>>>(qh, ql, Ktl, Vth, Vtl, out);
}

// Round 6
// 285.047 us; speedup vs baseline: 2.1657x; 2.1657x over previous
//
#include <hip/hip_runtime.h>

typedef __attribute__((ext_vector_type(8))) short short8;
typedef __attribute__((ext_vector_type(8))) _Float16 half8;
typedef __attribute__((ext_vector_type(4))) float f32x4;
typedef __attribute__((ext_vector_type(4))) unsigned short u16x4;

#define NB 8
#define NQL 2048
#define NKL 2048
#define DD 512

static __device__ __forceinline__ unsigned short f2bf(float x){
  unsigned u = __builtin_bit_cast(unsigned, x);
  unsigned r = u + 0x7FFFu + ((u >> 16) & 1u);
  return (unsigned short)(r >> 16);
}
static __device__ __forceinline__ float bf2f(unsigned short h){
  unsigned u = ((unsigned)h) << 16;
  return __builtin_bit_cast(float, u);
}

static __device__ __forceinline__ void stage16(const void* g, void* l){
  __builtin_amdgcn_global_load_lds(
      (const __attribute__((address_space(1))) void*)g,
      (__attribute__((address_space(3))) void*)l, 16, 0, 0);
}

static __device__ __forceinline__ void barrier_lgkm(){
  asm volatile("s_waitcnt lgkmcnt(0)" ::: "memory");
  __builtin_amdgcn_s_barrier();
  asm volatile("" ::: "memory");
}

// ---------------- split fp32 -> bf16 hi/lo (W matrices only) ----------------
__global__ __launch_bounds__(256) void split_k(const float* __restrict__ x,
    unsigned short* __restrict__ hi, unsigned short* __restrict__ lo, int n4){
  int i = blockIdx.x*256 + threadIdx.x;
  if (i >= n4) return;
  f32x4 v = reinterpret_cast<const f32x4*>(x)[i];
  u16x4 h, l;
  #pragma unroll
  for (int j=0;j<4;j++){
    unsigned short hh = f2bf(v[j]);
    h[j] = hh;
    l[j] = f2bf(v[j] - bf2f(hh));
  }
  reinterpret_cast<u16x4*>(hi)[i] = h;
  reinterpret_cast<u16x4*>(lo)[i] = l;
}

// ---------------- fused projections: Y = X * W^T (128x128 tile, staged, dbuf) ----------------
// z=0: Q flat hi/lo [16384][512] (bf16 bits)
// z=1: K tiles [b][kt][2][32][512] bf16 hi/lo, col-group ^ (row&7)
// z=2: V tiles [b][kt][512][32] fp16 SINGLE, k-slot ^ ((dcol>>1)&3)
__global__ __launch_bounds__(256, 2) void proj2_k(
    const float* __restrict__ Xq, const float* __restrict__ Xk, const float* __restrict__ Xv,
    const unsigned short* __restrict__ Wqh, const unsigned short* __restrict__ Wql,
    const unsigned short* __restrict__ Wkh, const unsigned short* __restrict__ Wkl,
    const unsigned short* __restrict__ Wvh, const unsigned short* __restrict__ Wvl,
    unsigned short* __restrict__ Yqh, unsigned short* __restrict__ Yql,
    unsigned short* __restrict__ Ykt,
    _Float16* __restrict__ Yvt)
{
  __shared__ unsigned short AB[2][4][128][32];   // 64 KB

  const int z = blockIdx.z;
  const float* X          = (z==0) ? Xq  : (z==1) ? Xk  : Xv;
  const unsigned short* Wh = (z==0) ? Wqh : (z==1) ? Wkh : Wvh;
  const unsigned short* Wl = (z==0) ? Wql : (z==1) ? Wkl : Wvl;

  const int mbase = blockIdx.x * 128;
  const int nbase = blockIdx.y * 128;
  const int tid = threadIdx.x;
  const int w = tid >> 6, lane = tid & 63;
  const int l15 = lane & 15, l4 = lane >> 4;
  const int wr = w >> 1, wc = w & 1;

  const int arow = tid >> 1, ahalf = tid & 1;
  const int brow_l = w*16 + (lane>>2);
  const int bkg    = (lane & 3) ^ ((lane >> 3) & 3);

  f32x4 acc[4][4];
  #pragma unroll
  for (int m=0;m<4;m++)
    #pragma unroll
    for (int n=0;n<4;n++) acc[m][n] = (f32x4){0.f,0.f,0.f,0.f};

  f32x4 xa[4];
  {
    const f32x4* xp = reinterpret_cast<const f32x4*>(X + (size_t)(mbase+arow)*DD + ahalf*16);
    #pragma unroll
    for (int q=0;q<4;q++) xa[q] = xp[q];
  }
  {
    unsigned short* lB = &AB[0][2][0][0] + w*512;
    #pragma unroll
    for (int r=0;r<2;r++){
      const size_t gh = (size_t)(nbase + r*64 + brow_l)*DD + bkg*8;
      stage16(Wh + gh, lB + r*2048);
      stage16(Wl + gh, lB + 4096 + r*2048);
    }
  }
  {
    asm volatile("s_waitcnt vmcnt(4)" ::: "memory");
    short8 h0,h1,l0,l1;
    #pragma unroll
    for (int q=0;q<2;q++){
      #pragma unroll
      for (int j=0;j<4;j++){
        float v0 = xa[q*2][j], v1 = xa[q*2+1][j];
        unsigned short a = f2bf(v0); unsigned short b = f2bf(v1);
        if (q==0){ h0[j]=(short)a; h0[4+j]=(short)b; l0[j]=(short)f2bf(v0-bf2f(a)); l0[4+j]=(short)f2bf(v1-bf2f(b)); }
        else     { h1[j]=(short)a; h1[4+j]=(short)b; l1[j]=(short)f2bf(v0-bf2f(a)); l1[4+j]=(short)f2bf(v1-bf2f(b)); }
      }
    }
    const int sw = (arow>>1)&3;
    const int cg0 = (ahalf*2) ^ sw, cg1 = (ahalf*2+1) ^ sw;
    *reinterpret_cast<short8*>(&AB[0][0][arow][cg0*8]) = h0;
    *reinterpret_cast<short8*>(&AB[0][0][arow][cg1*8]) = h1;
    *reinterpret_cast<short8*>(&AB[0][1][arow][cg0*8]) = l0;
    *reinterpret_cast<short8*>(&AB[0][1][arow][cg1*8]) = l1;
  }

  const int asw = (l15>>1)&3;

  #pragma unroll 1
  for (int s=0; s<16; ++s){
    const int cur = s&1, nxt = cur^1;
    asm volatile("s_waitcnt vmcnt(0)" ::: "memory");
    barrier_lgkm();

    if (s < 15){
      const f32x4* xp = reinterpret_cast<const f32x4*>(X + (size_t)(mbase+arow)*DD + (s+1)*32 + ahalf*16);
      #pragma unroll
      for (int q=0;q<4;q++) xa[q] = xp[q];
      unsigned short* lB = &AB[nxt][2][0][0] + w*512;
      #pragma unroll
      for (int r=0;r<2;r++){
        const size_t gh = (size_t)(nbase + r*64 + brow_l)*DD + (s+1)*32 + bkg*8;
        stage16(Wh + gh, lB + r*2048);
        stage16(Wl + gh, lB + 4096 + r*2048);
      }
    }

    short8 ah[4], al[4], bh[4], bl[4];
    #pragma unroll
    for (int m=0;m<4;m++){
      const int rA = wr*64 + m*16 + l15;
      const int cg = (l4 ^ asw)*8;
      ah[m] = *reinterpret_cast<const short8*>(&AB[cur][0][rA][cg]);
      al[m] = *reinterpret_cast<const short8*>(&AB[cur][1][rA][cg]);
    }
    #pragma unroll
    for (int n=0;n<4;n++){
      const int rB = wc*64 + n*16 + l15;
      const int cg = (l4 ^ asw)*8;
      bh[n] = *reinterpret_cast<const short8*>(&AB[cur][2][rB][cg]);
      bl[n] = *reinterpret_cast<const short8*>(&AB[cur][3][rB][cg]);
    }
    #pragma unroll
    for (int m=0;m<4;m++)
      #pragma unroll
      for (int n=0;n<4;n++) acc[m][n] = __builtin_amdgcn_mfma_f32_16x16x32_bf16(ah[m], bh[n], acc[m][n], 0,0,0);
    #pragma unroll
    for (int m=0;m<4;m++)
      #pragma unroll
      for (int n=0;n<4;n++) acc[m][n] = __builtin_amdgcn_mfma_f32_16x16x32_bf16(ah[m], bl[n], acc[m][n], 0,0,0);
    #pragma unroll
    for (int m=0;m<4;m++)
      #pragma unroll
      for (int n=0;n<4;n++) acc[m][n] = __builtin_amdgcn_mfma_f32_16x16x32_bf16(al[m], bh[n], acc[m][n], 0,0,0);

    if (s < 15){
      asm volatile("s_waitcnt vmcnt(4)" ::: "memory");
      short8 h0,h1,l0,l1;
      #pragma unroll
      for (int q=0;q<2;q++){
        #pragma unroll
        for (int j=0;j<4;j++){
          float v0 = xa[q*2][j], v1 = xa[q*2+1][j];
          unsigned short a = f2bf(v0); unsigned short b = f2bf(v1);
          if (q==0){ h0[j]=(short)a; h0[4+j]=(short)b; l0[j]=(short)f2bf(v0-bf2f(a)); l0[4+j]=(short)f2bf(v1-bf2f(b)); }
          else     { h1[j]=(short)a; h1[4+j]=(short)b; l1[j]=(short)f2bf(v0-bf2f(a)); l1[4+j]=(short)f2bf(v1-bf2f(b)); }
        }
      }
      const int sw = (arow>>1)&3;
      const int cg0 = (ahalf*2) ^ sw, cg1 = (ahalf*2+1) ^ sw;
      *reinterpret_cast<short8*>(&AB[nxt][0][arow][cg0*8]) = h0;
      *reinterpret_cast<short8*>(&AB[nxt][0][arow][cg1*8]) = h1;
      *reinterpret_cast<short8*>(&AB[nxt][1][arow][cg0*8]) = l0;
      *reinterpret_cast<short8*>(&AB[nxt][1][arow][cg1*8]) = l1;
    }
  }

  #pragma unroll
  for (int m=0;m<4;m++){
    #pragma unroll
    for (int n=0;n<4;n++){
      #pragma unroll
      for (int j=0;j<4;j++){
        const int row = mbase + wr*64 + m*16 + l4*4 + j;
        const int col = nbase + wc*64 + n*16 + l15;
        const float y = acc[m][n][j];
        if (z == 0){
          const unsigned short h = f2bf(y);
          const unsigned short l = f2bf(y - bf2f(h));
          const size_t idx = (size_t)row*DD + col;
          Yqh[idx] = h; Yql[idx] = l;
        } else if (z == 1){
          const unsigned short h = f2bf(y);
          const unsigned short l = f2bf(y - bf2f(h));
          const int bb = row >> 11, nn = row & 2047, kt = nn >> 5;
          const size_t tb = ((size_t)(bb*64 + kt)) << 15;
          const int kr = nn & 31, cg = col >> 3, ci = col & 7;
          const size_t idxH = tb + ((size_t)kr)*512 + (size_t)((((cg ^ (kr & 7)) << 3)) | ci);
          Ykt[idxH] = h; Ykt[idxH + 16384] = l;
        } else {
          const int bb = row >> 11, nn = row & 2047, kt = nn >> 5;
          const size_t tb = ((size_t)(bb*64 + kt)) << 14;   // 16384 fp16/tile
          const int kk = nn & 31;
          const size_t idx = tb + ((size_t)col)*32 + (size_t)(((((kk >> 3) ^ ((col >> 1) & 3)) << 3)) | (kk & 7));
          Yvt[idx] = (_Float16)y;
        }
      }
    }
  }
}

// ---------------- fused flash attention ----------------
// K single-buffered LDS (bf16 hi/lo, staged post-barB, ~half-step lead).
// V double-buffered LDS (SINGLE fp16, staged post-barA, full-step lead).
// P single fp16. PV: 2 MFMA per cc (f16). QK^T: bf16 3-pass (unchanged).
__global__ __launch_bounds__(512, 2) void attn_k(
    const unsigned short* __restrict__ Qhi, const unsigned short* __restrict__ Qlo,
    const unsigned short* __restrict__ Kt,
    const _Float16* __restrict__ Vt,
    float* __restrict__ Out)
{
  __shared__ unsigned short K_lds[2][32][512];   // 64 KB (hi/lo, row, swizzled col)
  __shared__ _Float16 V_lds[2][512][32];         // 64 KB dbuf (fp16 single)
  __shared__ _Float16 P_s[64][40];               // 5 KB
  __shared__ float pm_s[64][2], ps_s[64][2];
  __shared__ float m_s[2][64], l_s[64], sc_s[64];

  const int bid = blockIdx.x;
  const int b  = bid & 7;
  const int qt = bid >> 3;
  const int tid = threadIdx.x;
  const int w = tid >> 6, lane = tid & 63;
  const int l15 = lane & 15, l4 = lane >> 4;
  const int rw = w & 3,  cw = w >> 2;   // S^T frag: q-rows rw*16.., k-cols cw*16..
  const int orw = w >> 2, ocw = w & 3;  // O: rows orw*32.., cols ocw*128..

  short8 qhf[16], qlf[16];
  {
    const size_t qoff = (size_t)(b*NQL + qt*64 + rw*16 + l15)*DD + l4*8;
    #pragma unroll
    for (int kc=0;kc<16;kc++){
      qhf[kc] = *reinterpret_cast<const short8*>(Qhi + qoff + kc*32);
      qlf[kc] = *reinterpret_cast<const short8*>(Qlo + qoff + kc*32);
    }
  }

  f32x4 o[2][8];
  #pragma unroll
  for (int i=0;i<2;i++)
    #pragma unroll
    for (int j=0;j<8;j++) o[i][j] = (f32x4){0.f,0.f,0.f,0.f};

  if (tid < 64){ m_s[0][tid] = -1e30f; l_s[tid] = 0.f; }

  const unsigned short* gK = Kt + ((size_t)(b*64) << 15);
  const _Float16*       gV = Vt + ((size_t)(b*64) << 14);
  const int goff  = w*512 + lane*8;   // elems
  const int lbase = w*512;            // wave-uniform dest base (elems)

  // prologue: stage K(0) [8 issues] + V(0) [4 issues]
  {
    unsigned short* lK = &K_lds[0][0][0];
    #pragma unroll
    for (int r=0;r<8;r++) stage16(gK + r*4096 + goff, lK + r*4096 + lbase);
    _Float16* lV = &V_lds[0][0][0];
    #pragma unroll
    for (int r=0;r<4;r++) stage16(gV + r*4096 + goff, lV + r*4096 + lbase);
  }

  const int krow = cw*16 + l15;
  const int kx = krow & 7;
  const int row_i = rw*16 + l15;     // this lane's q-row (local)

  #pragma unroll 1
  for (int kt=0; kt<64; ++kt){
    const int par = kt & 1;
    asm volatile("s_waitcnt vmcnt(0)" ::: "memory");   // K(kt), V(kt) resident
    barrier_lgkm();                                    // bar A

    // stage V(kt+1) into the other V buffer — full-step lead
    {
      const _Float16* g = gV + ((size_t)((kt+1)&63) << 14);
      _Float16* lV = &V_lds[par^1][0][0];
      #pragma unroll
      for (int r=0;r<4;r++) stage16(g + r*4096 + goff, lV + r*4096 + lbase);
    }

    // ---- S^T = K Q^T (swapped operands, bf16 3-pass) ----
    f32x4 shh = (f32x4){0.f,0.f,0.f,0.f};
    f32x4 shl = (f32x4){0.f,0.f,0.f,0.f};
    f32x4 slh = (f32x4){0.f,0.f,0.f,0.f};
    __builtin_amdgcn_s_setprio(1);
    #pragma unroll
    for (int kc=0;kc<16;kc++){
      const int cg = ((kc*4 + l4) ^ kx) << 3;
      const short8 kh = *reinterpret_cast<const short8*>(&K_lds[0][krow][cg]);
      const short8 kl = *reinterpret_cast<const short8*>(&K_lds[1][krow][cg]);
      shh = __builtin_amdgcn_mfma_f32_16x16x32_bf16(kh, qhf[kc], shh, 0,0,0);
      shl = __builtin_amdgcn_mfma_f32_16x16x32_bf16(kl, qhf[kc], shl, 0,0,0);
      slh = __builtin_amdgcn_mfma_f32_16x16x32_bf16(kh, qlf[kc], slh, 0,0,0);
    }
    __builtin_amdgcn_s_setprio(0);
    const f32x4 sv = shh + shl + slh;   // sv[r] = S[row_i][cw*16 + l4*4 + r]

    // ---- per-wave softmax partials ----
    float mw = fmaxf(fmaxf(sv[0],sv[1]), fmaxf(sv[2],sv[3]));
    mw = fmaxf(mw, __shfl_xor(mw, 16));
    mw = fmaxf(mw, __shfl_xor(mw, 32));
    float p0 = __expf(sv[0]-mw), p1 = __expf(sv[1]-mw);
    float p2 = __expf(sv[2]-mw), p3 = __expf(sv[3]-mw);
    float ssum = p0+p1+p2+p3;
    ssum += __shfl_xor(ssum, 16);
    ssum += __shfl_xor(ssum, 32);
    if (l4 == 0){ pm_s[row_i][cw] = mw; ps_s[row_i][cw] = ssum; }
    barrier_lgkm();                                    // bar B — partials ready, K_lds free

    // stage K(kt+1) into the single K buffer — hidden under combine + PV
    {
      const unsigned short* g = gK + ((size_t)((kt+1)&63) << 15);
      unsigned short* lK = &K_lds[0][0][0];
      #pragma unroll
      for (int r=0;r<8;r++) stage16(g + r*4096 + goff, lK + r*4096 + lbase);
    }

    // ---- combine partials, finalize P (single fp16), write ----
    {
      const float m0 = pm_s[row_i][0], m1 = pm_s[row_i][1];
      const float m_old = m_s[par][row_i];
      const float m_new = fmaxf(fmaxf(m0, m1), m_old);
      const float c = __expf(mw - m_new);
      p0 *= c; p1 *= c; p2 *= c; p3 *= c;
      if (cw == 0 && l4 == 0){
        const float e_old = __expf(m_old - m_new);
        const float e1    = __expf(m1 - m_new);
        l_s[row_i] = l_s[row_i]*e_old + ps_s[row_i][0]*c + ps_s[row_i][1]*e1;
        m_s[par^1][row_i] = m_new;
        sc_s[row_i] = e_old;
      }
      const unsigned short h0 = __builtin_bit_cast(unsigned short, (_Float16)p0);
      const unsigned short h1 = __builtin_bit_cast(unsigned short, (_Float16)p1);
      const unsigned short h2 = __builtin_bit_cast(unsigned short, (_Float16)p2);
      const unsigned short h3 = __builtin_bit_cast(unsigned short, (_Float16)p3);
      uint2 hv;
      hv.x = (unsigned)h0 | ((unsigned)h1<<16);
      hv.y = (unsigned)h2 | ((unsigned)h3<<16);
      *reinterpret_cast<uint2*>(&P_s[row_i][cw*16 + l4*4]) = hv;
    }
    barrier_lgkm();                                    // bar C — P ready, V(kt) ready

    // ---- rescale O (skip when running max unchanged) ----
    {
      float scs[2][4];
      bool need = false;
      #pragma unroll
      for (int pr=0; pr<2; pr++)
        #pragma unroll
        for (int j=0;j<4;j++){
          const float s0 = sc_s[orw*32 + pr*16 + l4*4 + j];
          scs[pr][j] = s0;
          need = need || (s0 < 0.999999f);
        }
      if (__any(need)){
        #pragma unroll
        for (int pr=0;pr<2;pr++)
          #pragma unroll
          for (int c=0;c<8;c++)
            #pragma unroll
            for (int j=0;j<4;j++) o[pr][c][j] *= scs[pr][j];
      }
    }

    // ---- O += P V (fp16 single-pass: 2 MFMA per cc) ----
    half8 pa[2];
    #pragma unroll
    for (int pr=0;pr<2;pr++){
      const int prow = orw*32 + pr*16 + l15;
      pa[pr] = *reinterpret_cast<const half8*>(&P_s[prow][l4*8]);
    }
    __builtin_amdgcn_s_setprio(1);
    #pragma unroll
    for (int cc=0; cc<8; ++cc){
      const int dcol = ocw*128 + cc*16 + l15;
      const int vb = (l4 ^ ((dcol>>1)&3)) << 3;
      const half8 vv = *reinterpret_cast<const half8*>(&V_lds[par][dcol][vb]);
      o[0][cc] = __builtin_amdgcn_mfma_f32_16x16x32_f16(pa[0], vv, o[0][cc], 0,0,0);
      o[1][cc] = __builtin_amdgcn_mfma_f32_16x16x32_f16(pa[1], vv, o[1][cc], 0,0,0);
    }
    __builtin_amdgcn_s_setprio(0);
    // no bar D: barA's lgkmcnt(0)+barrier orders P/V reuse; V buffers parity-split
  }

  barrier_lgkm();   // l_s final visible

  #pragma unroll
  for (int pr=0;pr<2;pr++){
    #pragma unroll
    for (int j=0;j<4;j++){
      const int row = orw*32 + pr*16 + l4*4 + j;
      const float inv = 1.0f / l_s[row];
      const size_t obase = (size_t)(b*NQL + qt*64 + row)*DD;
      #pragma unroll
      for (int c=0;c<8;c++){
        const int col = ocw*128 + c*16 + l15;
        Out[obase + col] = o[pr][c][j]*inv;
      }
    }
  }
}

extern "C" void kernel_launch(void* const* d_in, const int* in_sizes, int n_in,
                              void* d_out, int out_size, void* d_ws, size_t ws_size,
                              hipStream_t stream) {
  const float* query = (const float*)d_in[0];
  const float* key   = (const float*)d_in[1];
  const float* value = (const float*)d_in[2];
  const float* Wq    = (const float*)d_in[3];
  const float* Wk    = (const float*)d_in[4];
  const float* Wv    = (const float*)d_in[5];
  float* out = (float*)d_out;

  const size_t SB = (size_t)NB*NQL*DD;   // 8,388,608 elems
  const size_t WB = (size_t)DD*DD;

  unsigned short* p = (unsigned short*)d_ws;
  unsigned short *wqh = p,        *wql = p +   WB;
  unsigned short *wkh = p + 2*WB, *wkl = p + 3*WB;
  unsigned short *wvh = p + 4*WB, *wvl = p + 5*WB;
  unsigned short* q0 = p + 6*WB;
  unsigned short *qh  = q0,        *ql  = q0 + SB;
  unsigned short *Ktl = q0 + 2*SB;                    // [8][64][2][32][512] bf16 = 2*SB
  _Float16       *Vtl = (_Float16*)(q0 + 4*SB);       // [8][64][512][32] fp16  = 1*SB slots

  split_k<<<256, 256, 0, stream>>>(Wq, wqh, wql, (int)(WB/4));
  split_k<<<256, 256, 0, stream>>>(Wk, wkh, wkl, (int)(WB/4));
  split_k<<<256, 256, 0, stream>>>(Wv, wvh, wvl, (int)(WB/4));

  dim3 pg(128, 4, 3);
  proj2_k<<<pg, 256, 0, stream>>>(query, key, value,
                                  wqh, wql, wkh, wkl, wvh, wvl,
                                  qh, ql, Ktl, Vtl);

  attn_k<<<256, 512, 0, stream>>>(qh, ql, Ktl, Vtl, out);
}

// Round 7
// 254.653 us; speedup vs baseline: 2.4242x; 1.1194x over previous
//
#include <hip/hip_runtime.h>

typedef __attribute__((ext_vector_type(8))) short short8;
typedef __attribute__((ext_vector_type(8))) _Float16 half8;
typedef __attribute__((ext_vector_type(4))) float f32x4;
typedef __attribute__((ext_vector_type(4))) unsigned short u16x4;

#define NB 8
#define NQL 2048
#define NKL 2048
#define DD 512

static __device__ __forceinline__ unsigned short f2bf(float x){
  unsigned u = __builtin_bit_cast(unsigned, x);
  unsigned r = u + 0x7FFFu + ((u >> 16) & 1u);
  return (unsigned short)(r >> 16);
}
static __device__ __forceinline__ float bf2f(unsigned short h){
  unsigned u = ((unsigned)h) << 16;
  return __builtin_bit_cast(float, u);
}

static __device__ __forceinline__ void stage16(const void* g, void* l){
  __builtin_amdgcn_global_load_lds(
      (const __attribute__((address_space(1))) void*)g,
      (__attribute__((address_space(3))) void*)l, 16, 0, 0);
}

static __device__ __forceinline__ void barrier_lgkm(){
  asm volatile("s_waitcnt lgkmcnt(0)" ::: "memory");
  __builtin_amdgcn_s_barrier();
  asm volatile("" ::: "memory");
}

// ---------------- split fp32 -> bf16 hi/lo, all three W in one launch ----------------
__global__ __launch_bounds__(256) void split3_k(
    const float* __restrict__ Wq, const float* __restrict__ Wk, const float* __restrict__ Wv,
    unsigned short* __restrict__ hiq, unsigned short* __restrict__ loq,
    unsigned short* __restrict__ hik, unsigned short* __restrict__ lok,
    unsigned short* __restrict__ hiv, unsigned short* __restrict__ lov, int n4){
  const int z = blockIdx.y;
  const float* x = (z==0) ? Wq : (z==1) ? Wk : Wv;
  unsigned short* hi = (z==0) ? hiq : (z==1) ? hik : hiv;
  unsigned short* lo = (z==0) ? loq : (z==1) ? lok : lov;
  int i = blockIdx.x*256 + threadIdx.x;
  if (i >= n4) return;
  f32x4 v = reinterpret_cast<const f32x4*>(x)[i];
  u16x4 h, l;
  #pragma unroll
  for (int j=0;j<4;j++){
    unsigned short hh = f2bf(v[j]);
    h[j] = hh;
    l[j] = f2bf(v[j] - bf2f(hh));
  }
  reinterpret_cast<u16x4*>(hi)[i] = h;
  reinterpret_cast<u16x4*>(lo)[i] = l;
}

// ---------------- fused projections: Y = X * W^T (128x128 tile, staged, dbuf) ----------------
// 3-pass split-bf16 MFMA core for all z (proj accuracy ~1e-4). Outputs:
// z=0: Q flat [16384][512], fp16 hi + fp16 lo (split of fp32 result)
// z=1: K tiles [b][kt][32][512] fp16 SINGLE, col-group ^ (row&7)
// z=2: V tiles [b][kt][512][32] fp16 SINGLE, k-slot ^ ((dcol>>1)&3)
__global__ __launch_bounds__(256, 2) void proj2_k(
    const float* __restrict__ Xq, const float* __restrict__ Xk, const float* __restrict__ Xv,
    const unsigned short* __restrict__ Wqh, const unsigned short* __restrict__ Wql,
    const unsigned short* __restrict__ Wkh, const unsigned short* __restrict__ Wkl,
    const unsigned short* __restrict__ Wvh, const unsigned short* __restrict__ Wvl,
    _Float16* __restrict__ Yqh, _Float16* __restrict__ Yql,
    _Float16* __restrict__ Ykt,
    _Float16* __restrict__ Yvt)
{
  __shared__ unsigned short AB[2][4][128][32];   // 64 KB

  const int z = blockIdx.z;
  const float* X          = (z==0) ? Xq  : (z==1) ? Xk  : Xv;
  const unsigned short* Wh = (z==0) ? Wqh : (z==1) ? Wkh : Wvh;
  const unsigned short* Wl = (z==0) ? Wql : (z==1) ? Wkl : Wvl;

  const int mbase = blockIdx.x * 128;
  const int nbase = blockIdx.y * 128;
  const int tid = threadIdx.x;
  const int w = tid >> 6, lane = tid & 63;
  const int l15 = lane & 15, l4 = lane >> 4;
  const int wr = w >> 1, wc = w & 1;

  const int arow = tid >> 1, ahalf = tid & 1;
  const int brow_l = w*16 + (lane>>2);
  const int bkg    = (lane & 3) ^ ((lane >> 3) & 3);

  f32x4 acc[4][4];
  #pragma unroll
  for (int m=0;m<4;m++)
    #pragma unroll
    for (int n=0;n<4;n++) acc[m][n] = (f32x4){0.f,0.f,0.f,0.f};

  f32x4 xa[4];
  {
    const f32x4* xp = reinterpret_cast<const f32x4*>(X + (size_t)(mbase+arow)*DD + ahalf*16);
    #pragma unroll
    for (int q=0;q<4;q++) xa[q] = xp[q];
  }
  {
    unsigned short* lB = &AB[0][2][0][0] + w*512;
    #pragma unroll
    for (int r=0;r<2;r++){
      const size_t gh = (size_t)(nbase + r*64 + brow_l)*DD + bkg*8;
      stage16(Wh + gh, lB + r*2048);
      stage16(Wl + gh, lB + 4096 + r*2048);
    }
  }
  {
    asm volatile("s_waitcnt vmcnt(4)" ::: "memory");
    short8 h0,h1,l0,l1;
    #pragma unroll
    for (int q=0;q<2;q++){
      #pragma unroll
      for (int j=0;j<4;j++){
        float v0 = xa[q*2][j], v1 = xa[q*2+1][j];
        unsigned short a = f2bf(v0); unsigned short b = f2bf(v1);
        if (q==0){ h0[j]=(short)a; h0[4+j]=(short)b; l0[j]=(short)f2bf(v0-bf2f(a)); l0[4+j]=(short)f2bf(v1-bf2f(b)); }
        else     { h1[j]=(short)a; h1[4+j]=(short)b; l1[j]=(short)f2bf(v0-bf2f(a)); l1[4+j]=(short)f2bf(v1-bf2f(b)); }
      }
    }
    const int sw = (arow>>1)&3;
    const int cg0 = (ahalf*2) ^ sw, cg1 = (ahalf*2+1) ^ sw;
    *reinterpret_cast<short8*>(&AB[0][0][arow][cg0*8]) = h0;
    *reinterpret_cast<short8*>(&AB[0][0][arow][cg1*8]) = h1;
    *reinterpret_cast<short8*>(&AB[0][1][arow][cg0*8]) = l0;
    *reinterpret_cast<short8*>(&AB[0][1][arow][cg1*8]) = l1;
  }

  const int asw = (l15>>1)&3;

  #pragma unroll 1
  for (int s=0; s<16; ++s){
    const int cur = s&1, nxt = cur^1;
    asm volatile("s_waitcnt vmcnt(0)" ::: "memory");
    barrier_lgkm();

    if (s < 15){
      const f32x4* xp = reinterpret_cast<const f32x4*>(X + (size_t)(mbase+arow)*DD + (s+1)*32 + ahalf*16);
      #pragma unroll
      for (int q=0;q<4;q++) xa[q] = xp[q];
      unsigned short* lB = &AB[nxt][2][0][0] + w*512;
      #pragma unroll
      for (int r=0;r<2;r++){
        const size_t gh = (size_t)(nbase + r*64 + brow_l)*DD + (s+1)*32 + bkg*8;
        stage16(Wh + gh, lB + r*2048);
        stage16(Wl + gh, lB + 4096 + r*2048);
      }
    }

    short8 ah[4], al[4], bh[4], bl[4];
    #pragma unroll
    for (int m=0;m<4;m++){
      const int rA = wr*64 + m*16 + l15;
      const int cg = (l4 ^ asw)*8;
      ah[m] = *reinterpret_cast<const short8*>(&AB[cur][0][rA][cg]);
      al[m] = *reinterpret_cast<const short8*>(&AB[cur][1][rA][cg]);
    }
    #pragma unroll
    for (int n=0;n<4;n++){
      const int rB = wc*64 + n*16 + l15;
      const int cg = (l4 ^ asw)*8;
      bh[n] = *reinterpret_cast<const short8*>(&AB[cur][2][rB][cg]);
      bl[n] = *reinterpret_cast<const short8*>(&AB[cur][3][rB][cg]);
    }
    #pragma unroll
    for (int m=0;m<4;m++)
      #pragma unroll
      for (int n=0;n<4;n++) acc[m][n] = __builtin_amdgcn_mfma_f32_16x16x32_bf16(ah[m], bh[n], acc[m][n], 0,0,0);
    #pragma unroll
    for (int m=0;m<4;m++)
      #pragma unroll
      for (int n=0;n<4;n++) acc[m][n] = __builtin_amdgcn_mfma_f32_16x16x32_bf16(ah[m], bl[n], acc[m][n], 0,0,0);
    #pragma unroll
    for (int m=0;m<4;m++)
      #pragma unroll
      for (int n=0;n<4;n++) acc[m][n] = __builtin_amdgcn_mfma_f32_16x16x32_bf16(al[m], bh[n], acc[m][n], 0,0,0);

    if (s < 15){
      asm volatile("s_waitcnt vmcnt(4)" ::: "memory");
      short8 h0,h1,l0,l1;
      #pragma unroll
      for (int q=0;q<2;q++){
        #pragma unroll
        for (int j=0;j<4;j++){
          float v0 = xa[q*2][j], v1 = xa[q*2+1][j];
          unsigned short a = f2bf(v0); unsigned short b = f2bf(v1);
          if (q==0){ h0[j]=(short)a; h0[4+j]=(short)b; l0[j]=(short)f2bf(v0-bf2f(a)); l0[4+j]=(short)f2bf(v1-bf2f(b)); }
          else     { h1[j]=(short)a; h1[4+j]=(short)b; l1[j]=(short)f2bf(v0-bf2f(a)); l1[4+j]=(short)f2bf(v1-bf2f(b)); }
        }
      }
      const int sw = (arow>>1)&3;
      const int cg0 = (ahalf*2) ^ sw, cg1 = (ahalf*2+1) ^ sw;
      *reinterpret_cast<short8*>(&AB[nxt][0][arow][cg0*8]) = h0;
      *reinterpret_cast<short8*>(&AB[nxt][0][arow][cg1*8]) = h1;
      *reinterpret_cast<short8*>(&AB[nxt][1][arow][cg0*8]) = l0;
      *reinterpret_cast<short8*>(&AB[nxt][1][arow][cg1*8]) = l1;
    }
  }

  #pragma unroll
  for (int m=0;m<4;m++){
    #pragma unroll
    for (int n=0;n<4;n++){
      #pragma unroll
      for (int j=0;j<4;j++){
        const int row = mbase + wr*64 + m*16 + l4*4 + j;
        const int col = nbase + wc*64 + n*16 + l15;
        const float y = acc[m][n][j];
        if (z == 0){
          const _Float16 h = (_Float16)y;
          const _Float16 l = (_Float16)(y - (float)h);
          const size_t idx = (size_t)row*DD + col;
          Yqh[idx] = h; Yql[idx] = l;
        } else if (z == 1){
          const int bb = row >> 11, nn = row & 2047, kt = nn >> 5;
          const size_t tb = ((size_t)(bb*64 + kt)) << 14;   // 16384 fp16/tile
          const int kr = nn & 31, cg = col >> 3, ci = col & 7;
          const size_t idx = tb + ((size_t)kr)*512 + (size_t)((((cg ^ (kr & 7)) << 3)) | ci);
          Ykt[idx] = (_Float16)y;
        } else {
          const int bb = row >> 11, nn = row & 2047, kt = nn >> 5;
          const size_t tb = ((size_t)(bb*64 + kt)) << 14;   // 16384 fp16/tile
          const int kk = nn & 31;
          const size_t idx = tb + ((size_t)col)*32 + (size_t)(((((kk >> 3) ^ ((col >> 1) & 3)) << 3)) | (kk & 7));
          Yvt[idx] = (_Float16)y;
        }
      }
    }
  }
}

// ---------------- fused flash attention ----------------
// K fp16 single, dbuf LDS. V fp16 single, dbuf LDS. Both staged at step top
// (full-step lead), ONE pre-drained vmcnt(0) per step. QK^T: 2-pass fp16
// (Q split hi/lo, exact; K rounded). PV: fp16. 3 barriers/step.
__global__ __launch_bounds__(512, 2) void attn_k(
    const _Float16* __restrict__ Qh, const _Float16* __restrict__ Ql,
    const _Float16* __restrict__ Kt,
    const _Float16* __restrict__ Vt,
    float* __restrict__ Out)
{
  __shared__ _Float16 K_lds[2][32][512];   // 64 KB dbuf (fp16 single, swizzled col)
  __shared__ _Float16 V_lds[2][512][32];   // 64 KB dbuf (fp16 single)
  __shared__ _Float16 P_s[64][40];         // 5 KB
  __shared__ float pm_s[64][2], ps_s[64][2];
  __shared__ float m_s[2][64], l_s[64], sc_s[64];

  const int bid = blockIdx.x;
  const int b  = bid & 7;
  const int qt = bid >> 3;
  const int tid = threadIdx.x;
  const int w = tid >> 6, lane = tid & 63;
  const int l15 = lane & 15, l4 = lane >> 4;
  const int rw = w & 3,  cw = w >> 2;   // S^T frag: q-rows rw*16.., k-cols cw*16..
  const int orw = w >> 2, ocw = w & 3;  // O: rows orw*32.., cols ocw*128..

  half8 qhf[16], qlf[16];
  {
    const size_t qoff = (size_t)(b*NQL + qt*64 + rw*16 + l15)*DD + l4*8;
    #pragma unroll
    for (int kc=0;kc<16;kc++){
      qhf[kc] = *reinterpret_cast<const half8*>(Qh + qoff + kc*32);
      qlf[kc] = *reinterpret_cast<const half8*>(Ql + qoff + kc*32);
    }
  }

  f32x4 o[2][8];
  #pragma unroll
  for (int i=0;i<2;i++)
    #pragma unroll
    for (int j=0;j<8;j++) o[i][j] = (f32x4){0.f,0.f,0.f,0.f};

  if (tid < 64){ m_s[0][tid] = -1e30f; l_s[tid] = 0.f; }

  const _Float16* gK = Kt + ((size_t)(b*64) << 14);
  const _Float16* gV = Vt + ((size_t)(b*64) << 14);
  const int goff  = w*512 + lane*8;   // fp16 elems
  const int lbase = w*512;            // wave-uniform dest base (fp16 elems)

  // prologue: stage K(0) + V(0) into buffers 0 (4+4 issues)
  {
    _Float16* lK = &K_lds[0][0][0];
    _Float16* lV = &V_lds[0][0][0];
    #pragma unroll
    for (int r=0;r<4;r++) stage16(gK + r*4096 + goff, lK + r*4096 + lbase);
    #pragma unroll
    for (int r=0;r<4;r++) stage16(gV + r*4096 + goff, lV + r*4096 + lbase);
  }

  const int krow = cw*16 + l15;
  const int kx = krow & 7;
  const int row_i = rw*16 + l15;     // this lane's q-row (local)

  #pragma unroll 1
  for (int kt=0; kt<64; ++kt){
    const int par = kt & 1;
    asm volatile("s_waitcnt vmcnt(0)" ::: "memory");   // K(kt), V(kt) resident (full-step lead)
    barrier_lgkm();                                    // bar A

    // stage K(kt+1)+V(kt+1) into the other buffers — full-step lead
    {
      const _Float16* gk1 = gK + ((size_t)((kt+1)&63) << 14);
      const _Float16* gv1 = gV + ((size_t)((kt+1)&63) << 14);
      _Float16* lK = &K_lds[par^1][0][0];
      _Float16* lV = &V_lds[par^1][0][0];
      #pragma unroll
      for (int r=0;r<4;r++) stage16(gk1 + r*4096 + goff, lK + r*4096 + lbase);
      #pragma unroll
      for (int r=0;r<4;r++) stage16(gv1 + r*4096 + goff, lV + r*4096 + lbase);
    }

    // ---- S^T = K Q^T (2-pass fp16: k single, q split) ----
    f32x4 shh = (f32x4){0.f,0.f,0.f,0.f};
    f32x4 shl = (f32x4){0.f,0.f,0.f,0.f};
    __builtin_amdgcn_s_setprio(1);
    #pragma unroll
    for (int kc=0;kc<16;kc++){
      const int cg = ((kc*4 + l4) ^ kx) << 3;
      const half8 kf = *reinterpret_cast<const half8*>(&K_lds[par][krow][cg]);
      shh = __builtin_amdgcn_mfma_f32_16x16x32_f16(kf, qhf[kc], shh, 0,0,0);
      shl = __builtin_amdgcn_mfma_f32_16x16x32_f16(kf, qlf[kc], shl, 0,0,0);
    }
    __builtin_amdgcn_s_setprio(0);
    const f32x4 sv = shh + shl;   // sv[r] = S[row_i][cw*16 + l4*4 + r]

    // ---- per-wave softmax partials ----
    float mw = fmaxf(fmaxf(sv[0],sv[1]), fmaxf(sv[2],sv[3]));
    mw = fmaxf(mw, __shfl_xor(mw, 16));
    mw = fmaxf(mw, __shfl_xor(mw, 32));
    float p0 = __expf(sv[0]-mw), p1 = __expf(sv[1]-mw);
    float p2 = __expf(sv[2]-mw), p3 = __expf(sv[3]-mw);
    float ssum = p0+p1+p2+p3;
    ssum += __shfl_xor(ssum, 16);
    ssum += __shfl_xor(ssum, 32);
    if (l4 == 0){ pm_s[row_i][cw] = mw; ps_s[row_i][cw] = ssum; }
    barrier_lgkm();                                    // bar B — partials ready

    // ---- combine partials, finalize P (fp16), write ----
    {
      const float m0 = pm_s[row_i][0], m1 = pm_s[row_i][1];
      const float m_old = m_s[par][row_i];
      const float m_new = fmaxf(fmaxf(m0, m1), m_old);
      const float c = __expf(mw - m_new);
      p0 *= c; p1 *= c; p2 *= c; p3 *= c;
      if (cw == 0 && l4 == 0){
        const float e_old = __expf(m_old - m_new);
        const float e1    = __expf(m1 - m_new);
        l_s[row_i] = l_s[row_i]*e_old + ps_s[row_i][0]*c + ps_s[row_i][1]*e1;
        m_s[par^1][row_i] = m_new;
        sc_s[row_i] = e_old;
      }
      const unsigned short h0 = __builtin_bit_cast(unsigned short, (_Float16)p0);
      const unsigned short h1 = __builtin_bit_cast(unsigned short, (_Float16)p1);
      const unsigned short h2 = __builtin_bit_cast(unsigned short, (_Float16)p2);
      const unsigned short h3 = __builtin_bit_cast(unsigned short, (_Float16)p3);
      uint2 hv;
      hv.x = (unsigned)h0 | ((unsigned)h1<<16);
      hv.y = (unsigned)h2 | ((unsigned)h3<<16);
      *reinterpret_cast<uint2*>(&P_s[row_i][cw*16 + l4*4]) = hv;
    }
    barrier_lgkm();                                    // bar C — P ready

    // ---- rescale O (skip when running max unchanged) ----
    {
      float scs[2][4];
      bool need = false;
      #pragma unroll
      for (int pr=0; pr<2; pr++)
        #pragma unroll
        for (int j=0;j<4;j++){
          const float s0 = sc_s[orw*32 + pr*16 + l4*4 + j];
          scs[pr][j] = s0;
          need = need || (s0 < 0.999999f);
        }
      if (__any(need)){
        #pragma unroll
        for (int pr=0;pr<2;pr++)
          #pragma unroll
          for (int c=0;c<8;c++)
            #pragma unroll
            for (int j=0;j<4;j++) o[pr][c][j] *= scs[pr][j];
      }
    }

    // ---- O += P V (fp16: 2 MFMA per cc) ----
    half8 pa[2];
    #pragma unroll
    for (int pr=0;pr<2;pr++){
      const int prow = orw*32 + pr*16 + l15;
      pa[pr] = *reinterpret_cast<const half8*>(&P_s[prow][l4*8]);
    }
    __builtin_amdgcn_s_setprio(1);
    #pragma unroll
    for (int cc=0; cc<8; ++cc){
      const int dcol = ocw*128 + cc*16 + l15;
      const int vb = (l4 ^ ((dcol>>1)&3)) << 3;
      const half8 vv = *reinterpret_cast<const half8*>(&V_lds[par][dcol][vb]);
      o[0][cc] = __builtin_amdgcn_mfma_f32_16x16x32_f16(pa[0], vv, o[0][cc], 0,0,0);
      o[1][cc] = __builtin_amdgcn_mfma_f32_16x16x32_f16(pa[1], vv, o[1][cc], 0,0,0);
    }
    __builtin_amdgcn_s_setprio(0);
    // no bar D: barA's lgkmcnt(0)+barrier orders P/K/V reuse; K,V parity-split
  }

  barrier_lgkm();   // l_s final visible

  #pragma unroll
  for (int pr=0;pr<2;pr++){
    #pragma unroll
    for (int j=0;j<4;j++){
      const int row = orw*32 + pr*16 + l4*4 + j;
      const float inv = 1.0f / l_s[row];
      const size_t obase = (size_t)(b*NQL + qt*64 + row)*DD;
      #pragma unroll
      for (int c=0;c<8;c++){
        const int col = ocw*128 + c*16 + l15;
        Out[obase + col] = o[pr][c][j]*inv;
      }
    }
  }
}

extern "C" void kernel_launch(void* const* d_in, const int* in_sizes, int n_in,
                              void* d_out, int out_size, void* d_ws, size_t ws_size,
                              hipStream_t stream) {
  const float* query = (const float*)d_in[0];
  const float* key   = (const float*)d_in[1];
  const float* value = (const float*)d_in[2];
  const float* Wq    = (const float*)d_in[3];
  const float* Wk    = (const float*)d_in[4];
  const float* Wv    = (const float*)d_in[5];
  float* out = (float*)d_out;

  const size_t SB = (size_t)NB*NQL*DD;   // 8,388,608 elems
  const size_t WB = (size_t)DD*DD;

  unsigned short* p = (unsigned short*)d_ws;
  unsigned short *wqh = p,        *wql = p +   WB;
  unsigned short *wkh = p + 2*WB, *wkl = p + 3*WB;
  unsigned short *wvh = p + 4*WB, *wvl = p + 5*WB;
  _Float16* q0 = (_Float16*)(p + 6*WB);
  _Float16 *qh16 = q0,          *ql16 = q0 + SB;
  _Float16 *Kt16 = q0 + 2*SB;                 // [8][64][32][512] fp16 = SB
  _Float16 *Vt16 = q0 + 3*SB;                 // [8][64][512][32] fp16 = SB

  dim3 sg(256, 3);
  split3_k<<<sg, 256, 0, stream>>>(Wq, Wk, Wv, wqh, wql, wkh, wkl, wvh, wvl, (int)(WB/4));

  dim3 pg(128, 4, 3);
  proj2_k<<<pg, 256, 0, stream>>>(query, key, value,
                                  wqh, wql, wkh, wkl, wvh, wvl,
                                  qh16, ql16, Kt16, Vt16);

  attn_k<<<256, 512, 0, stream>>>(qh16, ql16, Kt16, Vt16, out);
}